// Round 4
// baseline (298.898 us; speedup 1.0000x reference)
//
#include <hip/hip_runtime.h>
#include <hip/hip_bf16.h>

#define NB 8
#define NT 2048
#define NE 1024
#define NH 64
#define NM (NB*NT)   // 16384 rows

typedef float f32x4 __attribute__((ext_vector_type(4)));
typedef __bf16 bf16x8 __attribute__((ext_vector_type(8)));

#define MFMA16(A,B,C) __builtin_amdgcn_mfma_f32_16x16x32_bf16(A,B,C,0,0,0)

__device__ __forceinline__ bf16x8 ldb8(const __bf16* p){
    return *reinterpret_cast<const bf16x8*>(p);
}

// ---------------------------------------------------------------------------
// Pack Wq|Wk|Wv (fp32 [1024][64] each) into hi/lo bf16 MFMA B-frag layout:
// idx = ((kt*12 + c)*64 + lane)*8 + i  ->  W_mat[kt*32 + (lane>>4)*8 + i][(c&3)*16 + (lane&15)]
// ---------------------------------------------------------------------------
__global__ void pack_w(const float* __restrict__ Wq, const float* __restrict__ Wk,
                       const float* __restrict__ Wv,
                       __bf16* __restrict__ wh, __bf16* __restrict__ wl)
{
    const int idx = blockIdx.x * 256 + threadIdx.x;
    if (idx >= 32*12*64*8) return;
    const int i    = idx & 7;
    const int l    = (idx >> 3) & 63;
    const int rest = idx >> 9;
    const int c    = rest % 12;
    const int kt   = rest / 12;
    const int mat  = c >> 2;
    const float* W = (mat == 0) ? Wq : (mat == 1) ? Wk : Wv;
    const int n = (c & 3) * 16 + (l & 15);
    const int k = kt * 32 + (l >> 4) * 8 + i;
    const float w = W[k * NH + n];
    const __bf16 hi = (__bf16)w;
    const __bf16 lo = (__bf16)(w - (float)hi);
    wh[idx] = hi;
    wl[idx] = lo;
}

// ---------------------------------------------------------------------------
// Fused QKV projection: x[16384,1024] @ W[1024,192] + bias.
// 256 blocks x 512 threads (8 waves): waves 0-3 coltiles 0-5, waves 4-7 coltiles 6-11.
// BM=64 rows, BK=64. Software-pipelined: W slice and x frags for it+1 are
// prefetched into registers while MFMA(it) runs; only ds_write+MFMA are serial.
// q scaled by 0.125 (softmax scale folded). v stored transposed [b][h][t] via
// LDS transpose staging (coalesced bf16x8 writeout, no 64-line scatter).
// HBM-bound on x (64 MB read once) -> ~10.4 us floor.
// ---------------------------------------------------------------------------
__global__ __launch_bounds__(512) void proj_qkv(
    const float* __restrict__ x,
    const __bf16* __restrict__ wh, const __bf16* __restrict__ wl,
    const float* __restrict__ bq, const float* __restrict__ bk, const float* __restrict__ bv,
    __bf16* __restrict__ qh, __bf16* __restrict__ ql,
    __bf16* __restrict__ kh, __bf16* __restrict__ kl,
    __bf16* __restrict__ vh, __bf16* __restrict__ vl)
{
    __shared__ __align__(16) __bf16 lds[24576];   // 48 KB: [hi 12288 | lo 12288]

    const int tid  = threadIdx.x;
    const int lane = tid & 63;
    const int wv   = tid >> 6;
    const int rt   = wv & 3;          // row sub-tile (16 rows)
    const int cg   = wv >> 2;         // col half (6 coltiles each)
    const int row0 = blockIdx.x * 64 + rt * 16;
    const int arow = row0 + (lane & 15);
    const int kgrp = (lane >> 4) * 8;

    f32x4 acc[6];
#pragma unroll
    for (int c = 0; c < 6; ++c) acc[c] = (f32x4){0.f, 0.f, 0.f, 0.f};

    // ---- prefetch registers ----
    uint4  wreg[6];
    float4 xr[4];

    {   // prologue: W(0) and x(0)
        const uint4* gh = reinterpret_cast<const uint4*>(wh);
        const uint4* gl = reinterpret_cast<const uint4*>(wl);
        wreg[0] = gh[tid];  wreg[1] = gh[tid + 512];  wreg[2] = gh[tid + 1024];
        wreg[3] = gl[tid];  wreg[4] = gl[tid + 512];  wreg[5] = gl[tid + 1024];
#pragma unroll
        for (int sub = 0; sub < 2; ++sub) {
            const float* xp = x + (size_t)arow * NE + sub * 32 + kgrp;
            xr[sub * 2]     = *reinterpret_cast<const float4*>(xp);
            xr[sub * 2 + 1] = *reinterpret_cast<const float4*>(xp + 4);
        }
    }

    for (int it = 0; it < 16; ++it) {
        __syncthreads();   // all waves done reading LDS of it-1
        {   // ds_write staged W(it) from regs
            uint4* s = reinterpret_cast<uint4*>(lds);
            s[tid]        = wreg[0];
            s[tid + 512]  = wreg[1];
            s[tid + 1024] = wreg[2];
            s[tid + 1536] = wreg[3];
            s[tid + 2048] = wreg[4];
            s[tid + 2560] = wreg[5];
        }
        __syncthreads();   // LDS(it) ready

        // convert x(it) regs -> bf16 hi/lo A-frags (before xr is overwritten)
        bf16x8 ah[2], al[2];
#pragma unroll
        for (int sub = 0; sub < 2; ++sub) {
            const float4 xa = xr[sub * 2];
            const float4 xb = xr[sub * 2 + 1];
            float vt[8] = {xa.x, xa.y, xa.z, xa.w, xb.x, xb.y, xb.z, xb.w};
#pragma unroll
            for (int i = 0; i < 8; ++i) {
                const __bf16 h = (__bf16)vt[i];
                ah[sub][i] = h;
                al[sub][i] = (__bf16)(vt[i] - (float)h);
            }
        }

        if (it < 15) {   // prefetch W(it+1) and x(it+1); latency hides under MFMA
            const uint4* gh = reinterpret_cast<const uint4*>(wh + (it + 1) * 12288);
            const uint4* gl = reinterpret_cast<const uint4*>(wl + (it + 1) * 12288);
            wreg[0] = gh[tid];  wreg[1] = gh[tid + 512];  wreg[2] = gh[tid + 1024];
            wreg[3] = gl[tid];  wreg[4] = gl[tid + 512];  wreg[5] = gl[tid + 1024];
#pragma unroll
            for (int sub = 0; sub < 2; ++sub) {
                const float* xp = x + (size_t)arow * NE + (it + 1) * 64 + sub * 32 + kgrp;
                xr[sub * 2]     = *reinterpret_cast<const float4*>(xp);
                xr[sub * 2 + 1] = *reinterpret_cast<const float4*>(xp + 4);
            }
        }

#pragma unroll
        for (int c6 = 0; c6 < 6; ++c6) {
            const int c = cg * 6 + c6;
#pragma unroll
            for (int sub = 0; sub < 2; ++sub) {
                const __bf16* bp = lds + sub * 6144 + (c * 64 + lane) * 8;
                const bf16x8 bh = ldb8(bp);
                const bf16x8 bl = ldb8(bp + 12288);
                acc[c6] = MFMA16(ah[sub], bh, acc[c6]);
                acc[c6] = MFMA16(ah[sub], bl, acc[c6]);
                acc[c6] = MFMA16(al[sub], bh, acc[c6]);
            }
        }
    }

    // ---- epilogue: bias, q-scale, hi/lo split ----
    __syncthreads();   // waves 0-3 finished reading LDS(15); LDS now reusable for v-staging

    const int nloc = lane & 15;
    const int tloc = rt * 16 + (lane >> 4) * 4;   // local row base (0..63)
#pragma unroll
    for (int c6 = 0; c6 < 6; ++c6) {
        const int c   = cg * 6 + c6;
        const int mat = c >> 2;
        const int n   = (c & 3) * 16 + nloc;
        const float bias = (mat == 0) ? bq[n] : (mat == 1) ? bk[n] : bv[n];
#pragma unroll
        for (int r = 0; r < 4; ++r) {
            const int t = row0 + (lane >> 4) * 4 + r;
            float v = acc[c6][r] + bias;
            if (mat == 0) v *= 0.125f;            // fold 1/sqrt(64)
            const __bf16 h = (__bf16)v;
            const __bf16 l = (__bf16)(v - (float)h);
            if (mat == 0)      { qh[(size_t)t*NH + n] = h; ql[(size_t)t*NH + n] = l; }
            else if (mat == 1) { kh[(size_t)t*NH + n] = h; kl[(size_t)t*NH + n] = l; }
            else {
                // v: stage transposed tile [n][t] in LDS (stride 72: bank = 4n + t/2)
                const int tl = tloc + r;
                lds[n * 72 + tl]        = h;
                lds[4608 + n * 72 + tl] = l;
            }
        }
    }

    __syncthreads();   // v-staging complete
    {   // cooperative coalesced writeout: 512 threads, vh then vl tile (8 KB each)
        const int b  = blockIdx.x >> 5;            // batch (32 blocks/batch)
        const int t0 = (blockIdx.x & 31) * 64;     // tile row base within batch
        const int n    = tid >> 3;
        const int toff = (tid & 7) * 8;
        const size_t ga = ((size_t)(b * NH + n)) * NT + t0 + toff;
        *reinterpret_cast<bf16x8*>(vh + ga) = ldb8(lds + n * 72 + toff);
        *reinterpret_cast<bf16x8*>(vl + ga) = ldb8(lds + 4608 + n * 72 + toff);
    }
}

// ---------------------------------------------------------------------------
// Causal flash attention. 256 blocks (b = bid&7 -> batch==XCD for L2 locality,
// qtile = bid>>3) x 512 threads. Waves 0-3: even KV steps; waves 4-7: odd
// (2-way split-K, lse-merge in LDS). P routed through XOR-swizzled
// wave-private LDS (hi|lo packed per dword). KV read direct from L2 (per-XCD
// resident, 1 MB/batch); 4 same-j waves share via L1.
// ---------------------------------------------------------------------------
__global__ __launch_bounds__(512) void attn(
    const __bf16* __restrict__ qh, const __bf16* __restrict__ ql,
    const __bf16* __restrict__ kh, const __bf16* __restrict__ kl,
    const __bf16* __restrict__ vh, const __bf16* __restrict__ vl,
    float* __restrict__ out)
{
    __shared__ __align__(16) unsigned int pbuf[8][1024];  // 32 KB P transit
    __shared__ float obuf[64][65];                        // merge (padded: no bank conflict)
    __shared__ float mlbuf[64][2];

    const int tid = threadIdx.x, lane = tid & 63, wv = tid >> 6;
    const int grp = wv >> 2, wr = wv & 3;
    const int b   = blockIdx.x & 7;
    const int qt  = blockIdx.x >> 3;
    const int q0  = qt * 64 + wr * 16;                    // within batch
    const int kgrp = (lane >> 4) * 8;
    const float C = 1.44269504088896f;

    bf16x8 aqh[2], aql[2];
    {
        const size_t qrow = (size_t)(b * NT + q0 + (lane & 15)) * NH;
#pragma unroll
        for (int sub = 0; sub < 2; ++sub) {
            aqh[sub] = ldb8(qh + qrow + sub * 32 + kgrp);
            aql[sub] = ldb8(ql + qrow + sub * 32 + kgrp);
        }
    }

    f32x4 o[4];
    float mrun[4], lrun[4];
#pragma unroll
    for (int h = 0; h < 4; ++h) o[h] = (f32x4){0.f, 0.f, 0.f, 0.f};
#pragma unroll
    for (int r = 0; r < 4; ++r) { mrun[r] = -1e30f; lrun[r] = 0.f; }

    for (int j = grp; j <= qt; j += 2) {
        // ---- S = Q K^T (scale folded into q) ----
        f32x4 s[4];
#pragma unroll
        for (int st = 0; st < 4; ++st) s[st] = (f32x4){0.f, 0.f, 0.f, 0.f};
        const size_t kbase = (size_t)(b * NT + j * 64) * NH;
        __builtin_amdgcn_s_setprio(1);
#pragma unroll
        for (int st = 0; st < 4; ++st) {
            const size_t krow = kbase + (size_t)(st * 16 + (lane & 15)) * NH + kgrp;
#pragma unroll
            for (int sub = 0; sub < 2; ++sub) {
                const bf16x8 bh = ldb8(kh + krow + sub * 32);
                const bf16x8 bl = ldb8(kl + krow + sub * 32);
                s[st] = MFMA16(aqh[sub], bh, s[st]);
                s[st] = MFMA16(aqh[sub], bl, s[st]);
                s[st] = MFMA16(aql[sub], bh, s[st]);
            }
        }
        __builtin_amdgcn_s_setprio(0);

        if (j == qt) {   // diagonal tile mask
#pragma unroll
            for (int st = 0; st < 4; ++st)
#pragma unroll
                for (int r = 0; r < 4; ++r) {
                    const int srel = st * 16 + (lane & 15);
                    const int qrel = wr * 16 + (lane >> 4) * 4 + r;
                    if (srel > qrel) s[st][r] = -1e30f;
                }
        }

        // ---- online softmax (each 16-lane group owns 4 q-rows) ----
        float p[4][4];
#pragma unroll
        for (int r = 0; r < 4; ++r) {
            float pm = fmaxf(fmaxf(s[0][r], s[1][r]), fmaxf(s[2][r], s[3][r]));
#pragma unroll
            for (int off = 1; off < 16; off <<= 1)
                pm = fmaxf(pm, __shfl_xor(pm, off));
            const float mn  = fmaxf(mrun[r], pm);
            const float fac = exp2f((mrun[r] - mn) * C);
            float rs = 0.f;
#pragma unroll
            for (int st = 0; st < 4; ++st) {
                const float e = exp2f((s[st][r] - mn) * C);
                p[st][r] = e; rs += e;
            }
#pragma unroll
            for (int off = 1; off < 16; off <<= 1)
                rs += __shfl_xor(rs, off);
            lrun[r] = lrun[r] * fac + rs;
            mrun[r] = mn;
#pragma unroll
            for (int h = 0; h < 4; ++h) o[h][r] *= fac;
        }

        // ---- P -> LDS (hi|lo packed, XOR-swizzled) ----
#pragma unroll
        for (int st = 0; st < 4; ++st)
#pragma unroll
            for (int r = 0; r < 4; ++r) {
                const int q_ = (lane >> 4) * 4 + r;
                const int s_ = st * 16 + (lane & 15);
                const float pv = p[st][r];
                const __bf16 hh = (__bf16)pv;
                const __bf16 lo = (__bf16)(pv - (float)hh);
                const unsigned int u =
                    (unsigned int)__builtin_bit_cast(unsigned short, hh) |
                    ((unsigned int)__builtin_bit_cast(unsigned short, lo) << 16);
                pbuf[wv][q_ * 64 + (s_ ^ ((q_ & 7) << 2))] = u;
            }

        // ---- O += P V ----
        const size_t vbase = (size_t)(b * NH) * NT + j * 64;
#pragma unroll
        for (int sub = 0; sub < 2; ++sub) {
            const int q_ = lane & 15;
            const int s0 = sub * 32 + kgrp;
            const int sw = (q_ & 7) << 2;
            const uint4 ua = *reinterpret_cast<const uint4*>(&pbuf[wv][q_ * 64 + (s0 ^ sw)]);
            const uint4 ub = *reinterpret_cast<const uint4*>(&pbuf[wv][q_ * 64 + ((s0 + 4) ^ sw)]);
            union U8 { bf16x8 v; unsigned short u[8]; };
            U8 Ph, Pl;
            Ph.u[0] = (unsigned short)ua.x;  Pl.u[0] = (unsigned short)(ua.x >> 16);
            Ph.u[1] = (unsigned short)ua.y;  Pl.u[1] = (unsigned short)(ua.y >> 16);
            Ph.u[2] = (unsigned short)ua.z;  Pl.u[2] = (unsigned short)(ua.z >> 16);
            Ph.u[3] = (unsigned short)ua.w;  Pl.u[3] = (unsigned short)(ua.w >> 16);
            Ph.u[4] = (unsigned short)ub.x;  Pl.u[4] = (unsigned short)(ub.x >> 16);
            Ph.u[5] = (unsigned short)ub.y;  Pl.u[5] = (unsigned short)(ub.y >> 16);
            Ph.u[6] = (unsigned short)ub.z;  Pl.u[6] = (unsigned short)(ub.z >> 16);
            Ph.u[7] = (unsigned short)ub.w;  Pl.u[7] = (unsigned short)(ub.w >> 16);
            __builtin_amdgcn_s_setprio(1);
#pragma unroll
            for (int ht = 0; ht < 4; ++ht) {
                const size_t va = vbase + (size_t)(ht * 16 + (lane & 15)) * NT + sub * 32 + kgrp;
                const bf16x8 bh = ldb8(vh + va);
                const bf16x8 bl = ldb8(vl + va);
                o[ht] = MFMA16(Ph.v, bh, o[ht]);
                o[ht] = MFMA16(Ph.v, bl, o[ht]);
                o[ht] = MFMA16(Pl.v, bh, o[ht]);
            }
            __builtin_amdgcn_s_setprio(0);
        }
    }

    // ---- merge the two KV-split halves ----
    if (grp == 1) {
#pragma unroll
        for (int r = 0; r < 4; ++r) {
            const int row = wr * 16 + (lane >> 4) * 4 + r;
            if ((lane & 15) == 0) { mlbuf[row][0] = mrun[r]; mlbuf[row][1] = lrun[r]; }
#pragma unroll
            for (int ht = 0; ht < 4; ++ht)
                obuf[row][ht * 16 + (lane & 15)] = o[ht][r];
        }
    }
    __syncthreads();
    if (grp == 0) {
#pragma unroll
        for (int r = 0; r < 4; ++r) {
            const int row = wr * 16 + (lane >> 4) * 4 + r;
            const float m2 = mlbuf[row][0], l2 = mlbuf[row][1];
            const float mn = fmaxf(mrun[r], m2);
            const float f1 = exp2f((mrun[r] - mn) * C);
            const float f2 = exp2f((m2 - mn) * C);
            const float li = 1.f / (lrun[r] * f1 + l2 * f2);
#pragma unroll
            for (int ht = 0; ht < 4; ++ht) {
                const float ov = (o[ht][r] * f1 + obuf[row][ht * 16 + (lane & 15)] * f2) * li;
                out[(size_t)(b * NT + qt * 64 + row) * NH + ht * 16 + (lane & 15)] = ov;
            }
        }
    }
}

// ---------------------------------------------------------------------------
extern "C" void kernel_launch(void* const* d_in, const int* in_sizes, int n_in,
                              void* d_out, int out_size, void* d_ws, size_t ws_size,
                              hipStream_t stream)
{
    (void)in_sizes; (void)n_in; (void)out_size; (void)ws_size;
    const float* x  = (const float*)d_in[0];
    const float* Wq = (const float*)d_in[1];
    const float* bq = (const float*)d_in[2];
    const float* Wk = (const float*)d_in[3];
    const float* bk = (const float*)d_in[4];
    const float* Wv = (const float*)d_in[5];
    const float* bv = (const float*)d_in[6];
    float* out = (float*)d_out;

    char* ws = (char*)d_ws;
    __bf16* wh = (__bf16*)(ws);                         //  393216 B
    __bf16* wl = (__bf16*)(ws + 393216);                //  393216 B
    __bf16* qh = (__bf16*)(ws + 786432);                // 2 MB each below
    __bf16* ql = (__bf16*)(ws + 786432 + 2097152ull);
    __bf16* kh = (__bf16*)(ws + 786432 + 2*2097152ull);
    __bf16* kl = (__bf16*)(ws + 786432 + 3*2097152ull);
    __bf16* vh = (__bf16*)(ws + 786432 + 4*2097152ull); // transposed [b][h][t]
    __bf16* vl = (__bf16*)(ws + 786432 + 5*2097152ull);

    hipLaunchKernelGGL(pack_w, dim3(768), dim3(256), 0, stream, Wq, Wk, Wv, wh, wl);
    hipLaunchKernelGGL(proj_qkv, dim3(256), dim3(512), 0, stream,
                       x, wh, wl, bq, bk, bv, qh, ql, kh, kl, vh, vl);
    hipLaunchKernelGGL(attn, dim3(256), dim3(512), 0, stream,
                       qh, ql, kh, kl, vh, vl, out);
}

// Round 7
// 295.955 us; speedup vs baseline: 1.0099x; 1.0099x over previous
//
#include <hip/hip_runtime.h>
#include <hip/hip_bf16.h>

#define NB 8
#define NT 2048
#define NE 1024
#define NH 64
#define NM (NB*NT)   // 16384 rows

typedef float f32x4 __attribute__((ext_vector_type(4)));
typedef __bf16 bf16x8 __attribute__((ext_vector_type(8)));

#define MFMA16(A,B,C) __builtin_amdgcn_mfma_f32_16x16x32_bf16(A,B,C,0,0,0)

__device__ __forceinline__ bf16x8 ldb8(const __bf16* p){
    return *reinterpret_cast<const bf16x8*>(p);
}

// ---------------------------------------------------------------------------
// Pack Wq|Wk|Wv (fp32 [1024][64] each) into hi/lo bf16 MFMA B-frag layout:
// idx = ((kt*12 + c)*64 + lane)*8 + i  ->  W_mat[kt*32 + (lane>>4)*8 + i][(c&3)*16 + (lane&15)]
// ---------------------------------------------------------------------------
__global__ void pack_w(const float* __restrict__ Wq, const float* __restrict__ Wk,
                       const float* __restrict__ Wv,
                       __bf16* __restrict__ wh, __bf16* __restrict__ wl)
{
    const int idx = blockIdx.x * 256 + threadIdx.x;
    if (idx >= 32*12*64*8) return;
    const int i    = idx & 7;
    const int l    = (idx >> 3) & 63;
    const int rest = idx >> 9;
    const int c    = rest % 12;
    const int kt   = rest / 12;
    const int mat  = c >> 2;
    const float* W = (mat == 0) ? Wq : (mat == 1) ? Wk : Wv;
    const int n = (c & 3) * 16 + (l & 15);
    const int k = kt * 32 + (l >> 4) * 8 + i;
    const float w = W[k * NH + n];
    const __bf16 hi = (__bf16)w;
    const __bf16 lo = (__bf16)(w - (float)hi);
    wh[idx] = hi;
    wl[idx] = lo;
}

// ---------------------------------------------------------------------------
// Fused QKV projection: x[16384,1024] @ W[1024,192] + bias.
// 256 blocks x 512 threads (8 waves). Software-pipelined (W + x prefetch by 1).
// q scaled by 0.125. v stored transposed [b][h][t] via LDS transpose staging.
// ---------------------------------------------------------------------------
__global__ __launch_bounds__(512) void proj_qkv(
    const float* __restrict__ x,
    const __bf16* __restrict__ wh, const __bf16* __restrict__ wl,
    const float* __restrict__ bq, const float* __restrict__ bk, const float* __restrict__ bv,
    __bf16* __restrict__ qh, __bf16* __restrict__ ql,
    __bf16* __restrict__ kh, __bf16* __restrict__ kl,
    __bf16* __restrict__ vh, __bf16* __restrict__ vl)
{
    __shared__ __align__(16) __bf16 lds[24576];   // 48 KB: [hi 12288 | lo 12288]

    const int tid  = threadIdx.x;
    const int lane = tid & 63;
    const int wv   = tid >> 6;
    const int rt   = wv & 3;          // row sub-tile (16 rows)
    const int cg   = wv >> 2;         // col half (6 coltiles each)
    const int row0 = blockIdx.x * 64 + rt * 16;
    const int arow = row0 + (lane & 15);
    const int kgrp = (lane >> 4) * 8;

    f32x4 acc[6];
#pragma unroll
    for (int c = 0; c < 6; ++c) acc[c] = (f32x4){0.f, 0.f, 0.f, 0.f};

    // ---- prefetch registers ----
    uint4  wreg[6];
    float4 xr[4];

    {   // prologue: W(0) and x(0)
        const uint4* gh = reinterpret_cast<const uint4*>(wh);
        const uint4* gl = reinterpret_cast<const uint4*>(wl);
        wreg[0] = gh[tid];  wreg[1] = gh[tid + 512];  wreg[2] = gh[tid + 1024];
        wreg[3] = gl[tid];  wreg[4] = gl[tid + 512];  wreg[5] = gl[tid + 1024];
#pragma unroll
        for (int sub = 0; sub < 2; ++sub) {
            const float* xp = x + (size_t)arow * NE + sub * 32 + kgrp;
            xr[sub * 2]     = *reinterpret_cast<const float4*>(xp);
            xr[sub * 2 + 1] = *reinterpret_cast<const float4*>(xp + 4);
        }
    }

    for (int it = 0; it < 16; ++it) {
        __syncthreads();   // all waves done reading LDS of it-1
        {   // ds_write staged W(it) from regs
            uint4* s = reinterpret_cast<uint4*>(lds);
            s[tid]        = wreg[0];
            s[tid + 512]  = wreg[1];
            s[tid + 1024] = wreg[2];
            s[tid + 1536] = wreg[3];
            s[tid + 2048] = wreg[4];
            s[tid + 2560] = wreg[5];
        }
        __syncthreads();   // LDS(it) ready

        // convert x(it) regs -> bf16 hi/lo A-frags (before xr is overwritten)
        bf16x8 ah[2], al[2];
#pragma unroll
        for (int sub = 0; sub < 2; ++sub) {
            const float4 xa = xr[sub * 2];
            const float4 xb = xr[sub * 2 + 1];
            float vt[8] = {xa.x, xa.y, xa.z, xa.w, xb.x, xb.y, xb.z, xb.w};
#pragma unroll
            for (int i = 0; i < 8; ++i) {
                const __bf16 h = (__bf16)vt[i];
                ah[sub][i] = h;
                al[sub][i] = (__bf16)(vt[i] - (float)h);
            }
        }

        if (it < 15) {   // prefetch W(it+1) and x(it+1); latency hides under MFMA
            const uint4* gh = reinterpret_cast<const uint4*>(wh + (it + 1) * 12288);
            const uint4* gl = reinterpret_cast<const uint4*>(wl + (it + 1) * 12288);
            wreg[0] = gh[tid];  wreg[1] = gh[tid + 512];  wreg[2] = gh[tid + 1024];
            wreg[3] = gl[tid];  wreg[4] = gl[tid + 512];  wreg[5] = gl[tid + 1024];
#pragma unroll
            for (int sub = 0; sub < 2; ++sub) {
                const float* xp = x + (size_t)arow * NE + (it + 1) * 64 + sub * 32 + kgrp;
                xr[sub * 2]     = *reinterpret_cast<const float4*>(xp);
                xr[sub * 2 + 1] = *reinterpret_cast<const float4*>(xp + 4);
            }
        }

#pragma unroll
        for (int c6 = 0; c6 < 6; ++c6) {
            const int c = cg * 6 + c6;
#pragma unroll
            for (int sub = 0; sub < 2; ++sub) {
                const __bf16* bp = lds + sub * 6144 + (c * 64 + lane) * 8;
                const bf16x8 bh = ldb8(bp);
                const bf16x8 bl = ldb8(bp + 12288);
                acc[c6] = MFMA16(ah[sub], bh, acc[c6]);
                acc[c6] = MFMA16(ah[sub], bl, acc[c6]);
                acc[c6] = MFMA16(al[sub], bh, acc[c6]);
            }
        }
    }

    // ---- epilogue: bias, q-scale, hi/lo split ----
    __syncthreads();   // waves 0-3 finished reading LDS(15); LDS now reusable for v-staging

    const int nloc = lane & 15;
    const int tloc = rt * 16 + (lane >> 4) * 4;   // local row base (0..63)
#pragma unroll
    for (int c6 = 0; c6 < 6; ++c6) {
        const int c   = cg * 6 + c6;
        const int mat = c >> 2;
        const int n   = (c & 3) * 16 + nloc;
        const float bias = (mat == 0) ? bq[n] : (mat == 1) ? bk[n] : bv[n];
#pragma unroll
        for (int r = 0; r < 4; ++r) {
            const int t = row0 + (lane >> 4) * 4 + r;
            float v = acc[c6][r] + bias;
            if (mat == 0) v *= 0.125f;            // fold 1/sqrt(64)
            const __bf16 h = (__bf16)v;
            const __bf16 l = (__bf16)(v - (float)h);
            if (mat == 0)      { qh[(size_t)t*NH + n] = h; ql[(size_t)t*NH + n] = l; }
            else if (mat == 1) { kh[(size_t)t*NH + n] = h; kl[(size_t)t*NH + n] = l; }
            else {
                // v: stage transposed tile [n][t] in LDS (stride 72: bank = 4n + t/2)
                const int tl = tloc + r;
                lds[n * 72 + tl]        = h;
                lds[4608 + n * 72 + tl] = l;
            }
        }
    }

    __syncthreads();   // v-staging complete
    {   // cooperative coalesced writeout: 512 threads, vh then vl tile (8 KB each)
        const int b  = blockIdx.x >> 5;            // batch (32 blocks/batch)
        const int t0 = (blockIdx.x & 31) * 64;     // tile row base within batch
        const int n    = tid >> 3;
        const int toff = (tid & 7) * 8;
        const size_t ga = ((size_t)(b * NH + n)) * NT + t0 + toff;
        *reinterpret_cast<bf16x8*>(vh + ga) = ldb8(lds + n * 72 + toff);
        *reinterpret_cast<bf16x8*>(vl + ga) = ldb8(lds + 4608 + n * 72 + toff);
    }
}

// ---------------------------------------------------------------------------
// Causal flash attention. 256 blocks (b = bid&7 -> batch==XCD, qtile = bid>>3)
// x 512 threads. Waves 0-3: even KV steps; waves 4-7: odd (2-way split-K).
// Batched register loads: all 16 K-halves loaded before the QK MFMAs (one
// vmcnt wait instead of 16 serialized L2 round-trips); all 16 V-halves issued
// BEFORE the softmax so their latency hides under the VALU work.
// launch_bounds(512,2) lets the allocator use up to 256 VGPR.
// ---------------------------------------------------------------------------
__global__ __launch_bounds__(512, 2) void attn(
    const __bf16* __restrict__ qh, const __bf16* __restrict__ ql,
    const __bf16* __restrict__ kh, const __bf16* __restrict__ kl,
    const __bf16* __restrict__ vh, const __bf16* __restrict__ vl,
    float* __restrict__ out)
{
    __shared__ __align__(16) unsigned int pbuf[8][1024];  // 32 KB P transit
    __shared__ float obuf[64][65];                        // merge (padded)
    __shared__ float mlbuf[64][2];

    const int tid = threadIdx.x, lane = tid & 63, wv = tid >> 6;
    const int grp = wv >> 2, wr = wv & 3;
    const int b   = blockIdx.x & 7;
    const int qt  = blockIdx.x >> 3;
    const int q0  = qt * 64 + wr * 16;                    // within batch
    const int kgrp = (lane >> 4) * 8;
    const float C = 1.44269504088896f;

    bf16x8 aqh[2], aql[2];
    {
        const size_t qrow = (size_t)(b * NT + q0 + (lane & 15)) * NH;
#pragma unroll
        for (int sub = 0; sub < 2; ++sub) {
            aqh[sub] = ldb8(qh + qrow + sub * 32 + kgrp);
            aql[sub] = ldb8(ql + qrow + sub * 32 + kgrp);
        }
    }

    f32x4 o[4];
    float mrun[4], lrun[4];
#pragma unroll
    for (int h = 0; h < 4; ++h) o[h] = (f32x4){0.f, 0.f, 0.f, 0.f};
#pragma unroll
    for (int r = 0; r < 4; ++r) { mrun[r] = -1e30f; lrun[r] = 0.f; }

    for (int j = grp; j <= qt; j += 2) {
        // ---- batched K-tile load: 16 independent 16B loads, ONE wait ----
        bf16x8 kbh[4][2], kbl[4][2];
        const size_t kbase = (size_t)(b * NT + j * 64) * NH;
#pragma unroll
        for (int st = 0; st < 4; ++st) {
            const size_t krow = kbase + (size_t)(st * 16 + (lane & 15)) * NH + kgrp;
#pragma unroll
            for (int sub = 0; sub < 2; ++sub) {
                kbh[st][sub] = ldb8(kh + krow + sub * 32);
                kbl[st][sub] = ldb8(kl + krow + sub * 32);
            }
        }

        // ---- S = Q K^T (scale folded into q) ----
        f32x4 s[4];
#pragma unroll
        for (int st = 0; st < 4; ++st) s[st] = (f32x4){0.f, 0.f, 0.f, 0.f};
        __builtin_amdgcn_s_setprio(1);
#pragma unroll
        for (int st = 0; st < 4; ++st) {
#pragma unroll
            for (int sub = 0; sub < 2; ++sub) {
                s[st] = MFMA16(aqh[sub], kbh[st][sub], s[st]);
                s[st] = MFMA16(aqh[sub], kbl[st][sub], s[st]);
                s[st] = MFMA16(aql[sub], kbh[st][sub], s[st]);
            }
        }
        __builtin_amdgcn_s_setprio(0);

        // ---- issue V-tile loads NOW; latency hides under mask+softmax ----
        bf16x8 vbh[2][4], vbl[2][4];
        const size_t vbase = (size_t)(b * NH) * NT + j * 64;
#pragma unroll
        for (int sub = 0; sub < 2; ++sub) {
#pragma unroll
            for (int ht = 0; ht < 4; ++ht) {
                const size_t va = vbase + (size_t)(ht * 16 + (lane & 15)) * NT + sub * 32 + kgrp;
                vbh[sub][ht] = ldb8(vh + va);
                vbl[sub][ht] = ldb8(vl + va);
            }
        }

        if (j == qt) {   // diagonal tile mask
#pragma unroll
            for (int st = 0; st < 4; ++st)
#pragma unroll
                for (int r = 0; r < 4; ++r) {
                    const int srel = st * 16 + (lane & 15);
                    const int qrel = wr * 16 + (lane >> 4) * 4 + r;
                    if (srel > qrel) s[st][r] = -1e30f;
                }
        }

        // ---- online softmax (each 16-lane group owns 4 q-rows) ----
        float p[4][4];
#pragma unroll
        for (int r = 0; r < 4; ++r) {
            float pm = fmaxf(fmaxf(s[0][r], s[1][r]), fmaxf(s[2][r], s[3][r]));
#pragma unroll
            for (int off = 1; off < 16; off <<= 1)
                pm = fmaxf(pm, __shfl_xor(pm, off));
            const float mn  = fmaxf(mrun[r], pm);
            const float fac = exp2f((mrun[r] - mn) * C);
            float rs = 0.f;
#pragma unroll
            for (int st = 0; st < 4; ++st) {
                const float e = exp2f((s[st][r] - mn) * C);
                p[st][r] = e; rs += e;
            }
#pragma unroll
            for (int off = 1; off < 16; off <<= 1)
                rs += __shfl_xor(rs, off);
            lrun[r] = lrun[r] * fac + rs;
            mrun[r] = mn;
#pragma unroll
            for (int h = 0; h < 4; ++h) o[h][r] *= fac;
        }

        // ---- P -> LDS (hi|lo packed, XOR-swizzled) ----
#pragma unroll
        for (int st = 0; st < 4; ++st)
#pragma unroll
            for (int r = 0; r < 4; ++r) {
                const int q_ = (lane >> 4) * 4 + r;
                const int s_ = st * 16 + (lane & 15);
                const float pv = p[st][r];
                const __bf16 hh = (__bf16)pv;
                const __bf16 lo = (__bf16)(pv - (float)hh);
                const unsigned int u =
                    (unsigned int)__builtin_bit_cast(unsigned short, hh) |
                    ((unsigned int)__builtin_bit_cast(unsigned short, lo) << 16);
                pbuf[wv][q_ * 64 + (s_ ^ ((q_ & 7) << 2))] = u;
            }

        // ---- O += P V (V already in registers) ----
#pragma unroll
        for (int sub = 0; sub < 2; ++sub) {
            const int q_ = lane & 15;
            const int s0 = sub * 32 + kgrp;
            const int sw = (q_ & 7) << 2;
            const uint4 ua = *reinterpret_cast<const uint4*>(&pbuf[wv][q_ * 64 + (s0 ^ sw)]);
            const uint4 ub = *reinterpret_cast<const uint4*>(&pbuf[wv][q_ * 64 + ((s0 + 4) ^ sw)]);
            union U8 { bf16x8 v; unsigned short u[8]; };
            U8 Ph, Pl;
            Ph.u[0] = (unsigned short)ua.x;  Pl.u[0] = (unsigned short)(ua.x >> 16);
            Ph.u[1] = (unsigned short)ua.y;  Pl.u[1] = (unsigned short)(ua.y >> 16);
            Ph.u[2] = (unsigned short)ua.z;  Pl.u[2] = (unsigned short)(ua.z >> 16);
            Ph.u[3] = (unsigned short)ua.w;  Pl.u[3] = (unsigned short)(ua.w >> 16);
            Ph.u[4] = (unsigned short)ub.x;  Pl.u[4] = (unsigned short)(ub.x >> 16);
            Ph.u[5] = (unsigned short)ub.y;  Pl.u[5] = (unsigned short)(ub.y >> 16);
            Ph.u[6] = (unsigned short)ub.z;  Pl.u[6] = (unsigned short)(ub.z >> 16);
            Ph.u[7] = (unsigned short)ub.w;  Pl.u[7] = (unsigned short)(ub.w >> 16);
            __builtin_amdgcn_s_setprio(1);
#pragma unroll
            for (int ht = 0; ht < 4; ++ht) {
                o[ht] = MFMA16(Ph.v, vbh[sub][ht], o[ht]);
                o[ht] = MFMA16(Ph.v, vbl[sub][ht], o[ht]);
                o[ht] = MFMA16(Pl.v, vbh[sub][ht], o[ht]);
            }
            __builtin_amdgcn_s_setprio(0);
        }
    }

    // ---- merge the two KV-split halves ----
    if (grp == 1) {
#pragma unroll
        for (int r = 0; r < 4; ++r) {
            const int row = wr * 16 + (lane >> 4) * 4 + r;
            if ((lane & 15) == 0) { mlbuf[row][0] = mrun[r]; mlbuf[row][1] = lrun[r]; }
#pragma unroll
            for (int ht = 0; ht < 4; ++ht)
                obuf[row][ht * 16 + (lane & 15)] = o[ht][r];
        }
    }
    __syncthreads();
    if (grp == 0) {
#pragma unroll
        for (int r = 0; r < 4; ++r) {
            const int row = wr * 16 + (lane >> 4) * 4 + r;
            const float m2 = mlbuf[row][0], l2 = mlbuf[row][1];
            const float mn = fmaxf(mrun[r], m2);
            const float f1 = exp2f((mrun[r] - mn) * C);
            const float f2 = exp2f((m2 - mn) * C);
            const float li = 1.f / (lrun[r] * f1 + l2 * f2);
#pragma unroll
            for (int ht = 0; ht < 4; ++ht) {
                const float ov = (o[ht][r] * f1 + obuf[row][ht * 16 + (lane & 15)] * f2) * li;
                out[(size_t)(b * NT + qt * 64 + row) * NH + ht * 16 + (lane & 15)] = ov;
            }
        }
    }
}

// ---------------------------------------------------------------------------
extern "C" void kernel_launch(void* const* d_in, const int* in_sizes, int n_in,
                              void* d_out, int out_size, void* d_ws, size_t ws_size,
                              hipStream_t stream)
{
    (void)in_sizes; (void)n_in; (void)out_size; (void)ws_size;
    const float* x  = (const float*)d_in[0];
    const float* Wq = (const float*)d_in[1];
    const float* bq = (const float*)d_in[2];
    const float* Wk = (const float*)d_in[3];
    const float* bk = (const float*)d_in[4];
    const float* Wv = (const float*)d_in[5];
    const float* bv = (const float*)d_in[6];
    float* out = (float*)d_out;

    char* ws = (char*)d_ws;
    __bf16* wh = (__bf16*)(ws);                         //  393216 B
    __bf16* wl = (__bf16*)(ws + 393216);                //  393216 B
    __bf16* qh = (__bf16*)(ws + 786432);                // 2 MB each below
    __bf16* ql = (__bf16*)(ws + 786432 + 2097152ull);
    __bf16* kh = (__bf16*)(ws + 786432 + 2*2097152ull);
    __bf16* kl = (__bf16*)(ws + 786432 + 3*2097152ull);
    __bf16* vh = (__bf16*)(ws + 786432 + 4*2097152ull); // transposed [b][h][t]
    __bf16* vl = (__bf16*)(ws + 786432 + 5*2097152ull);

    hipLaunchKernelGGL(pack_w, dim3(768), dim3(256), 0, stream, Wq, Wk, Wv, wh, wl);
    hipLaunchKernelGGL(proj_qkv, dim3(256), dim3(512), 0, stream,
                       x, wh, wl, bq, bk, bv, qh, ql, kh, kl, vh, vl);
    hipLaunchKernelGGL(attn, dim3(256), dim3(512), 0, stream,
                       qh, ql, kh, kl, vh, vl, out);
}

// Round 10
// 259.114 us; speedup vs baseline: 1.1535x; 1.1422x over previous
//
#include <hip/hip_runtime.h>
#include <hip/hip_bf16.h>

#define NB 8
#define NT 2048
#define NE 1024
#define NH 64
#define NM (NB*NT)   // 16384 rows

typedef float f32x4 __attribute__((ext_vector_type(4)));
typedef __bf16 bf16x8 __attribute__((ext_vector_type(8)));

#define MFMA16(A,B,C) __builtin_amdgcn_mfma_f32_16x16x32_bf16(A,B,C,0,0,0)

__device__ __forceinline__ bf16x8 ldb8(const __bf16* p){
    return *reinterpret_cast<const bf16x8*>(p);
}

// ---------------------------------------------------------------------------
// Pack Wq|Wk|Wv (fp32 [1024][64] each) into hi/lo bf16 MFMA B-frag layout.
// ---------------------------------------------------------------------------
__global__ void pack_w(const float* __restrict__ Wq, const float* __restrict__ Wk,
                       const float* __restrict__ Wv,
                       __bf16* __restrict__ wh, __bf16* __restrict__ wl)
{
    const int idx = blockIdx.x * 256 + threadIdx.x;
    if (idx >= 32*12*64*8) return;
    const int i    = idx & 7;
    const int l    = (idx >> 3) & 63;
    const int rest = idx >> 9;
    const int c    = rest % 12;
    const int kt   = rest / 12;
    const int mat  = c >> 2;
    const float* W = (mat == 0) ? Wq : (mat == 1) ? Wk : Wv;
    const int n = (c & 3) * 16 + (l & 15);
    const int k = kt * 32 + (l >> 4) * 8 + i;
    const float w = W[k * NH + n];
    const __bf16 hi = (__bf16)w;
    const __bf16 lo = (__bf16)(w - (float)hi);
    wh[idx] = hi;
    wl[idx] = lo;
}

// ---------------------------------------------------------------------------
// Fused QKV projection: x[16384,1024] @ W[1024,192] + bias.
// launch_bounds(512,2): min 2 waves/EU -> VGPR cap 256. Without it the
// allocator capped at 64 VGPR and spilled the prefetch regs to scratch
// (r7: WRITE_SIZE 73.6MB vs 12MB expected, Occupancy 1%, 199.6us).
// ---------------------------------------------------------------------------
__global__ __launch_bounds__(512, 2) void proj_qkv(
    const float* __restrict__ x,
    const __bf16* __restrict__ wh, const __bf16* __restrict__ wl,
    const float* __restrict__ bq, const float* __restrict__ bk, const float* __restrict__ bv,
    __bf16* __restrict__ qh, __bf16* __restrict__ ql,
    __bf16* __restrict__ kh, __bf16* __restrict__ kl,
    __bf16* __restrict__ vh, __bf16* __restrict__ vl)
{
    __shared__ __align__(16) __bf16 lds[24576];   // 48 KB: [hi 12288 | lo 12288]

    const int tid  = threadIdx.x;
    const int lane = tid & 63;
    const int wv   = tid >> 6;
    const int rt   = wv & 3;          // row sub-tile (16 rows)
    const int cg   = wv >> 2;         // col half (6 coltiles each)
    const int row0 = blockIdx.x * 64 + rt * 16;
    const int arow = row0 + (lane & 15);
    const int kgrp = (lane >> 4) * 8;

    f32x4 acc[6];
#pragma unroll
    for (int c = 0; c < 6; ++c) acc[c] = (f32x4){0.f, 0.f, 0.f, 0.f};

    uint4  wreg[6];
    float4 xr[4];

    {   // prologue: W(0) and x(0)
        const uint4* gh = reinterpret_cast<const uint4*>(wh);
        const uint4* gl = reinterpret_cast<const uint4*>(wl);
        wreg[0] = gh[tid];  wreg[1] = gh[tid + 512];  wreg[2] = gh[tid + 1024];
        wreg[3] = gl[tid];  wreg[4] = gl[tid + 512];  wreg[5] = gl[tid + 1024];
#pragma unroll
        for (int sub = 0; sub < 2; ++sub) {
            const float* xp = x + (size_t)arow * NE + sub * 32 + kgrp;
            xr[sub * 2]     = *reinterpret_cast<const float4*>(xp);
            xr[sub * 2 + 1] = *reinterpret_cast<const float4*>(xp + 4);
        }
    }

    for (int it = 0; it < 16; ++it) {
        __syncthreads();
        {   // ds_write staged W(it) from regs
            uint4* s = reinterpret_cast<uint4*>(lds);
            s[tid]        = wreg[0];
            s[tid + 512]  = wreg[1];
            s[tid + 1024] = wreg[2];
            s[tid + 1536] = wreg[3];
            s[tid + 2048] = wreg[4];
            s[tid + 2560] = wreg[5];
        }
        __syncthreads();

        bf16x8 ah[2], al[2];
#pragma unroll
        for (int sub = 0; sub < 2; ++sub) {
            const float4 xa = xr[sub * 2];
            const float4 xb = xr[sub * 2 + 1];
            float vt[8] = {xa.x, xa.y, xa.z, xa.w, xb.x, xb.y, xb.z, xb.w};
#pragma unroll
            for (int i = 0; i < 8; ++i) {
                const __bf16 h = (__bf16)vt[i];
                ah[sub][i] = h;
                al[sub][i] = (__bf16)(vt[i] - (float)h);
            }
        }

        if (it < 15) {   // prefetch W(it+1) and x(it+1)
            const uint4* gh = reinterpret_cast<const uint4*>(wh + (it + 1) * 12288);
            const uint4* gl = reinterpret_cast<const uint4*>(wl + (it + 1) * 12288);
            wreg[0] = gh[tid];  wreg[1] = gh[tid + 512];  wreg[2] = gh[tid + 1024];
            wreg[3] = gl[tid];  wreg[4] = gl[tid + 512];  wreg[5] = gl[tid + 1024];
#pragma unroll
            for (int sub = 0; sub < 2; ++sub) {
                const float* xp = x + (size_t)arow * NE + (it + 1) * 64 + sub * 32 + kgrp;
                xr[sub * 2]     = *reinterpret_cast<const float4*>(xp);
                xr[sub * 2 + 1] = *reinterpret_cast<const float4*>(xp + 4);
            }
        }

#pragma unroll
        for (int c6 = 0; c6 < 6; ++c6) {
            const int c = cg * 6 + c6;
#pragma unroll
            for (int sub = 0; sub < 2; ++sub) {
                const __bf16* bp = lds + sub * 6144 + (c * 64 + lane) * 8;
                const bf16x8 bh = ldb8(bp);
                const bf16x8 bl = ldb8(bp + 12288);
                acc[c6] = MFMA16(ah[sub], bh, acc[c6]);
                acc[c6] = MFMA16(ah[sub], bl, acc[c6]);
                acc[c6] = MFMA16(al[sub], bh, acc[c6]);
            }
        }
    }

    // ---- epilogue: bias, q-scale, hi/lo split ----
    __syncthreads();

    const int nloc = lane & 15;
    const int tloc = rt * 16 + (lane >> 4) * 4;
#pragma unroll
    for (int c6 = 0; c6 < 6; ++c6) {
        const int c   = cg * 6 + c6;
        const int mat = c >> 2;
        const int n   = (c & 3) * 16 + nloc;
        const float bias = (mat == 0) ? bq[n] : (mat == 1) ? bk[n] : bv[n];
#pragma unroll
        for (int r = 0; r < 4; ++r) {
            const int t = row0 + (lane >> 4) * 4 + r;
            float v = acc[c6][r] + bias;
            if (mat == 0) v *= 0.125f;
            const __bf16 h = (__bf16)v;
            const __bf16 l = (__bf16)(v - (float)h);
            if (mat == 0)      { qh[(size_t)t*NH + n] = h; ql[(size_t)t*NH + n] = l; }
            else if (mat == 1) { kh[(size_t)t*NH + n] = h; kl[(size_t)t*NH + n] = l; }
            else {
                const int tl = tloc + r;
                lds[n * 72 + tl]        = h;
                lds[4608 + n * 72 + tl] = l;
            }
        }
    }

    __syncthreads();
    {   // coalesced v writeout
        const int b  = blockIdx.x >> 5;
        const int t0 = (blockIdx.x & 31) * 64;
        const int n    = tid >> 3;
        const int toff = (tid & 7) * 8;
        const size_t ga = ((size_t)(b * NH + n)) * NT + t0 + toff;
        *reinterpret_cast<bf16x8*>(vh + ga) = ldb8(lds + n * 72 + toff);
        *reinterpret_cast<bf16x8*>(vl + ga) = ldb8(lds + 4608 + n * 72 + toff);
    }
}

// ---------------------------------------------------------------------------
// Causal flash attention, v8: TLP restructure. r7 showed 121us with 1 block/CU
// (grid 256 = CU count), Occupancy 12%, MfmaUtil 4% — per-step load
// serialization (~18K cy/step) with nothing to overlap. Now: 16-row q-tiles ->
// 1024 blocks x 128 threads (2 waves: even/odd KV split, lse-merge). >=4
// independent blocks/CU hide each other's L2 stalls; causal tail (qt 0..127)
// load-balances across CUs. Per-step body verbatim from the verified kernel.
// ---------------------------------------------------------------------------
__global__ __launch_bounds__(128, 2) void attn(
    const __bf16* __restrict__ qh, const __bf16* __restrict__ ql,
    const __bf16* __restrict__ kh, const __bf16* __restrict__ kl,
    const __bf16* __restrict__ vh, const __bf16* __restrict__ vl,
    float* __restrict__ out)
{
    __shared__ __align__(16) unsigned int pbuf[2][1024];  // 8 KB P transit
    __shared__ float obuf[16][65];                        // merge (padded)
    __shared__ float mlbuf[16][2];

    const int tid = threadIdx.x, lane = tid & 63, wv = tid >> 6;
    const int grp = wv;                                   // KV split: even/odd j
    const int b   = blockIdx.x & 7;
    const int qt  = blockIdx.x >> 3;                      // 16-row tile (0..127)
    const int q0  = qt * 16;                              // within batch
    const int kgrp = (lane >> 4) * 8;
    const int jmax = (qt * 16 + 15) >> 6;                 // last KV step
    const float C = 1.44269504088896f;

    bf16x8 aqh[2], aql[2];
    {
        const size_t qrow = (size_t)(b * NT + q0 + (lane & 15)) * NH;
#pragma unroll
        for (int sub = 0; sub < 2; ++sub) {
            aqh[sub] = ldb8(qh + qrow + sub * 32 + kgrp);
            aql[sub] = ldb8(ql + qrow + sub * 32 + kgrp);
        }
    }

    f32x4 o[4];
    float mrun[4], lrun[4];
#pragma unroll
    for (int h = 0; h < 4; ++h) o[h] = (f32x4){0.f, 0.f, 0.f, 0.f};
#pragma unroll
    for (int r = 0; r < 4; ++r) { mrun[r] = -1e30f; lrun[r] = 0.f; }

    for (int j = grp; j <= jmax; j += 2) {
        // ---- batched K-tile load ----
        bf16x8 kbh[4][2], kbl[4][2];
        const size_t kbase = (size_t)(b * NT + j * 64) * NH;
#pragma unroll
        for (int st = 0; st < 4; ++st) {
            const size_t krow = kbase + (size_t)(st * 16 + (lane & 15)) * NH + kgrp;
#pragma unroll
            for (int sub = 0; sub < 2; ++sub) {
                kbh[st][sub] = ldb8(kh + krow + sub * 32);
                kbl[st][sub] = ldb8(kl + krow + sub * 32);
            }
        }

        // ---- S = Q K^T (scale folded into q) ----
        f32x4 s[4];
#pragma unroll
        for (int st = 0; st < 4; ++st) s[st] = (f32x4){0.f, 0.f, 0.f, 0.f};
        __builtin_amdgcn_s_setprio(1);
#pragma unroll
        for (int st = 0; st < 4; ++st) {
#pragma unroll
            for (int sub = 0; sub < 2; ++sub) {
                s[st] = MFMA16(aqh[sub], kbh[st][sub], s[st]);
                s[st] = MFMA16(aqh[sub], kbl[st][sub], s[st]);
                s[st] = MFMA16(aql[sub], kbh[st][sub], s[st]);
            }
        }
        __builtin_amdgcn_s_setprio(0);

        // ---- issue V-tile loads NOW; latency hides under mask+softmax ----
        bf16x8 vbh[2][4], vbl[2][4];
        const size_t vbase = (size_t)(b * NH) * NT + j * 64;
#pragma unroll
        for (int sub = 0; sub < 2; ++sub) {
#pragma unroll
            for (int ht = 0; ht < 4; ++ht) {
                const size_t va = vbase + (size_t)(ht * 16 + (lane & 15)) * NT + sub * 32 + kgrp;
                vbh[sub][ht] = ldb8(vh + va);
                vbl[sub][ht] = ldb8(vl + va);
            }
        }

        if (j == jmax) {   // only the last step can touch the diagonal
#pragma unroll
            for (int st = 0; st < 4; ++st)
#pragma unroll
                for (int r = 0; r < 4; ++r) {
                    const int srel = j * 64 + st * 16 + (lane & 15);   // global col
                    const int qrel = q0 + (lane >> 4) * 4 + r;         // global row
                    if (srel > qrel) s[st][r] = -1e30f;
                }
        }

        // ---- online softmax (each 16-lane group owns 4 q-rows) ----
        float p[4][4];
#pragma unroll
        for (int r = 0; r < 4; ++r) {
            float pm = fmaxf(fmaxf(s[0][r], s[1][r]), fmaxf(s[2][r], s[3][r]));
#pragma unroll
            for (int off = 1; off < 16; off <<= 1)
                pm = fmaxf(pm, __shfl_xor(pm, off));
            const float mn  = fmaxf(mrun[r], pm);
            const float fac = exp2f((mrun[r] - mn) * C);
            float rs = 0.f;
#pragma unroll
            for (int st = 0; st < 4; ++st) {
                const float e = exp2f((s[st][r] - mn) * C);
                p[st][r] = e; rs += e;
            }
#pragma unroll
            for (int off = 1; off < 16; off <<= 1)
                rs += __shfl_xor(rs, off);
            lrun[r] = lrun[r] * fac + rs;
            mrun[r] = mn;
#pragma unroll
            for (int h = 0; h < 4; ++h) o[h][r] *= fac;
        }

        // ---- P -> LDS (hi|lo packed, XOR-swizzled) ----
#pragma unroll
        for (int st = 0; st < 4; ++st)
#pragma unroll
            for (int r = 0; r < 4; ++r) {
                const int q_ = (lane >> 4) * 4 + r;
                const int s_ = st * 16 + (lane & 15);
                const float pv = p[st][r];
                const __bf16 hh = (__bf16)pv;
                const __bf16 lo = (__bf16)(pv - (float)hh);
                const unsigned int u =
                    (unsigned int)__builtin_bit_cast(unsigned short, hh) |
                    ((unsigned int)__builtin_bit_cast(unsigned short, lo) << 16);
                pbuf[wv][q_ * 64 + (s_ ^ ((q_ & 7) << 2))] = u;
            }

        // ---- O += P V (V already in registers) ----
#pragma unroll
        for (int sub = 0; sub < 2; ++sub) {
            const int q_ = lane & 15;
            const int s0 = sub * 32 + kgrp;
            const int sw = (q_ & 7) << 2;
            const uint4 ua = *reinterpret_cast<const uint4*>(&pbuf[wv][q_ * 64 + (s0 ^ sw)]);
            const uint4 ub = *reinterpret_cast<const uint4*>(&pbuf[wv][q_ * 64 + ((s0 + 4) ^ sw)]);
            union U8 { bf16x8 v; unsigned short u[8]; };
            U8 Ph, Pl;
            Ph.u[0] = (unsigned short)ua.x;  Pl.u[0] = (unsigned short)(ua.x >> 16);
            Ph.u[1] = (unsigned short)ua.y;  Pl.u[1] = (unsigned short)(ua.y >> 16);
            Ph.u[2] = (unsigned short)ua.z;  Pl.u[2] = (unsigned short)(ua.z >> 16);
            Ph.u[3] = (unsigned short)ua.w;  Pl.u[3] = (unsigned short)(ua.w >> 16);
            Ph.u[4] = (unsigned short)ub.x;  Pl.u[4] = (unsigned short)(ub.x >> 16);
            Ph.u[5] = (unsigned short)ub.y;  Pl.u[5] = (unsigned short)(ub.y >> 16);
            Ph.u[6] = (unsigned short)ub.z;  Pl.u[6] = (unsigned short)(ub.z >> 16);
            Ph.u[7] = (unsigned short)ub.w;  Pl.u[7] = (unsigned short)(ub.w >> 16);
            __builtin_amdgcn_s_setprio(1);
#pragma unroll
            for (int ht = 0; ht < 4; ++ht) {
                o[ht] = MFMA16(Ph.v, vbh[sub][ht], o[ht]);
                o[ht] = MFMA16(Ph.v, vbl[sub][ht], o[ht]);
                o[ht] = MFMA16(Pl.v, vbh[sub][ht], o[ht]);
            }
            __builtin_amdgcn_s_setprio(0);
        }
    }

    // ---- merge the two KV-split halves ----
    if (wv == 1) {
#pragma unroll
        for (int r = 0; r < 4; ++r) {
            const int row = (lane >> 4) * 4 + r;
            if ((lane & 15) == 0) { mlbuf[row][0] = mrun[r]; mlbuf[row][1] = lrun[r]; }
#pragma unroll
            for (int ht = 0; ht < 4; ++ht)
                obuf[row][ht * 16 + (lane & 15)] = o[ht][r];
        }
    }
    __syncthreads();
    if (wv == 0) {
#pragma unroll
        for (int r = 0; r < 4; ++r) {
            const int row = (lane >> 4) * 4 + r;
            const float m2 = mlbuf[row][0], l2 = mlbuf[row][1];
            const float mn = fmaxf(mrun[r], m2);
            const float f1 = exp2f((mrun[r] - mn) * C);
            const float f2 = exp2f((m2 - mn) * C);
            const float li = 1.f / (lrun[r] * f1 + l2 * f2);
#pragma unroll
            for (int ht = 0; ht < 4; ++ht) {
                const float ov = (o[ht][r] * f1 + obuf[row][ht * 16 + (lane & 15)] * f2) * li;
                out[(size_t)(b * NT + q0 + row) * NH + ht * 16 + (lane & 15)] = ov;
            }
        }
    }
}

// ---------------------------------------------------------------------------
extern "C" void kernel_launch(void* const* d_in, const int* in_sizes, int n_in,
                              void* d_out, int out_size, void* d_ws, size_t ws_size,
                              hipStream_t stream)
{
    (void)in_sizes; (void)n_in; (void)out_size; (void)ws_size;
    const float* x  = (const float*)d_in[0];
    const float* Wq = (const float*)d_in[1];
    const float* bq = (const float*)d_in[2];
    const float* Wk = (const float*)d_in[3];
    const float* bk = (const float*)d_in[4];
    const float* Wv = (const float*)d_in[5];
    const float* bv = (const float*)d_in[6];
    float* out = (float*)d_out;

    char* ws = (char*)d_ws;
    __bf16* wh = (__bf16*)(ws);                         //  393216 B
    __bf16* wl = (__bf16*)(ws + 393216);                //  393216 B
    __bf16* qh = (__bf16*)(ws + 786432);                // 2 MB each below
    __bf16* ql = (__bf16*)(ws + 786432 + 2097152ull);
    __bf16* kh = (__bf16*)(ws + 786432 + 2*2097152ull);
    __bf16* kl = (__bf16*)(ws + 786432 + 3*2097152ull);
    __bf16* vh = (__bf16*)(ws + 786432 + 4*2097152ull); // transposed [b][h][t]
    __bf16* vl = (__bf16*)(ws + 786432 + 5*2097152ull);

    hipLaunchKernelGGL(pack_w, dim3(768), dim3(256), 0, stream, Wq, Wk, Wv, wh, wl);
    hipLaunchKernelGGL(proj_qkv, dim3(256), dim3(512), 0, stream,
                       x, wh, wl, bq, bk, bv, qh, ql, kh, kl, vh, vl);
    hipLaunchKernelGGL(attn, dim3(1024), dim3(128), 0, stream,
                       qh, ql, kh, kl, vh, vl, out);
}